// Round 12
// baseline (133.877 us; speedup 1.0000x reference)
//
#include <hip/hip_runtime.h>
#include <hip/hip_bf16.h>

#define R_RES 384
#define S_SEQ 128
#define CM 256
#define CC 32
#define CZ 128

typedef __attribute__((ext_vector_type(8))) short bf16x8;
typedef __attribute__((ext_vector_type(4))) float f32x4;
typedef __attribute__((ext_vector_type(16))) float f32x16;
typedef __attribute__((ext_vector_type(4))) int i32x4;

__device__ __forceinline__ short tobf16(float f) {
    union { __hip_bfloat16 h; short s; } u;
    u.h = __float2bfloat16(f);
    return u.s;
}

// lgkm-only barrier: LDS visibility without draining outstanding global loads
__device__ __forceinline__ void lgkm_barrier() {
    asm volatile("s_waitcnt lgkmcnt(0)" ::: "memory");
    __builtin_amdgcn_s_barrier();
    __builtin_amdgcn_sched_barrier(0);
}

// ---------------- kernel 0a: w_out (1024,128) f32 -> wbTf 32x32x16-B-frag tiled bf16 ------
// frag(fz, k16), lane l: z = fz*32 + (l&31), k = k16*16 + (l>>5)*8 + j   (fz 0..3, k16 0..63)
__global__ void k_transpose_wout(const float* __restrict__ w_out, short* __restrict__ wbTf) {
    __shared__ float t[64][65];
    int k0 = blockIdx.x * 64;   // 16 blocks over k=1024
    int z0 = blockIdx.y * 64;   // 2 blocks over z=128
    int tid = threadIdx.x;
    int c = tid & 63, rg = tid >> 6;
#pragma unroll
    for (int rr = 0; rr < 16; ++rr) {
        int kk = rg * 16 + rr;
        t[kk][c] = w_out[(size_t)(k0 + kk) * CZ + z0 + c];
    }
    __syncthreads();
#pragma unroll
    for (int l = 0; l < 2; ++l) {
        int id = l * 256 + tid;
        int f = id >> 6;               // 0..7
        int ksl = f >> 1, fzl = f & 1;
        int ln = id & 63;
        int zl = fzl * 32 + (ln & 31);
        int kl = ksl * 16 + (ln >> 5) * 8;
        bf16x8 pk;
#pragma unroll
        for (int j = 0; j < 8; ++j) pk[j] = tobf16(t[kl + j][zl]);
        size_t fz = blockIdx.y * 2 + fzl;
        size_t k16 = blockIdx.x * 4 + ksl;
        *(bf16x8*)(wbTf + ((fz * 64 + k16) * 64 + ln) * 8) = pk;
    }
}

// ---------------- kernel 0b: pack w1|w2 (256,32) -> wcT (64,256) bf16 ----------------
__global__ void k_pack_w12(const float* __restrict__ w1, const float* __restrict__ w2,
                           short* __restrict__ wcT) {
    int idx = blockIdx.x * 256 + threadIdx.x;
    int k = idx >> 6, n = idx & 63;
    float v = (n < 32) ? w1[k * CC + n] : w2[k * CC + (n - 32)];
    wcT[n * CM + k] = tobf16(v);
}

// ---------------- kernel 1: LayerNorm + projections -> aTf, bTf 32-row-frag tiled bf16 ------
// res r, frag ks16 (0..7), lane l: row = r*32 + (l&31), s = ks16*16 + (l>>5)*8 + j
__global__ __launch_bounds__(256) void k_ln_proj(
    const float* __restrict__ M, const float* __restrict__ ln_g, const float* __restrict__ ln_b,
    const float* __restrict__ b1, const float* __restrict__ b2,
    const short* __restrict__ wcT, short* __restrict__ aTf, short* __restrict__ bTf) {
    __shared__ short mnb[64 * 256];      // [s_loc][k] bf16, XOR-swizzled, 32 KB
    __shared__ short ab_s[2][32 * 72];   // [x][s_loc] stride-72 transpose buffers
    int r = blockIdx.x >> 1;
    int s0 = (blockIdx.x & 1) * 64;
    int tid = threadIdx.x, lane = tid & 63, w = tid >> 6;
    int g = lane >> 4, r16 = lane & 15;
    float4 gv = *(const float4*)(ln_g + lane * 4);
    float4 bv = *(const float4*)(ln_b + lane * 4);
    for (int it = 0; it < 16; ++it) {
        int sl = it * 4 + w;
        float4 v = *(const float4*)(M + ((size_t)(s0 + sl) * R_RES + r) * CM + lane * 4);
        float sum = v.x + v.y + v.z + v.w;
        float sq = v.x * v.x + v.y * v.y + v.z * v.z + v.w * v.w;
#pragma unroll
        for (int off = 32; off; off >>= 1) {
            sum += __shfl_xor(sum, off);
            sq  += __shfl_xor(sq, off);
        }
        float mu = sum * (1.0f / 256.0f);
        float var = sq * (1.0f / 256.0f) - mu * mu;
        float rstd = rsqrtf(var + 1e-5f);
        short4 mnp;
        mnp.x = tobf16((v.x - mu) * rstd * gv.x + bv.x);
        mnp.y = tobf16((v.y - mu) * rstd * gv.y + bv.y);
        mnp.z = tobf16((v.z - mu) * rstd * gv.z + bv.z);
        mnp.w = tobf16((v.w - mu) * rstd * gv.w + bv.w);
        int byte = sl * 512 + lane * 8;
        byte ^= ((sl & 7) << 4);
        *(short4*)((char*)mnb + byte) = mnp;
    }
    __syncthreads();
    f32x4 acc[4] = {{0,0,0,0},{0,0,0,0},{0,0,0,0},{0,0,0,0}};
    int srow = w * 16 + r16;
#pragma unroll
    for (int ks = 0; ks < 8; ++ks) {
        int byte = srow * 512 + ks * 64 + g * 16;
        byte ^= ((srow & 7) << 4);
        bf16x8 af = *(const bf16x8*)((const char*)mnb + byte);
#pragma unroll
        for (int nt = 0; nt < 4; ++nt) {
            bf16x8 bf = *(const bf16x8*)(wcT + (nt * 16 + r16) * CM + ks * 32 + g * 8);
            acc[nt] = __builtin_amdgcn_mfma_f32_16x16x32_bf16(af, bf, acc[nt], 0, 0, 0);
        }
    }
#pragma unroll
    for (int nt = 0; nt < 4; ++nt) {
        int n = nt * 16 + r16;
        int x = n & 31, sel = n >> 5;
        float bias = sel ? b2[x] : b1[x];
#pragma unroll
        for (int rr = 0; rr < 4; ++rr) {
            int sl = w * 16 + g * 4 + rr;
            ab_s[sel][x * 72 + sl] = tobf16(acc[nt][rr] + bias);
        }
    }
    __syncthreads();
    // 32-row-frag write-out: frag ks16 = (tid>>6)*2 + f; n = ln&31, s = ks16*16 + (ln>>5)*8
#pragma unroll
    for (int f = 0; f < 2; ++f) {
        int ks16 = (tid >> 6) * 2 + f;
        int ln = tid & 63;
        int xr = ln & 31;
        int sx = ks16 * 16 + (ln >> 5) * 8;
        // only s-half [s0, s0+64) lives in this block: frag s ranges ks16*16.. -> global frag
        // index = (s0>>4) + ks16? No: each block covers 64 s = 4 frags of 16 s.
        // ks16 here is local 0..7 over 128 s total; this block owns s [s0, s0+64) i.e.
        // local frags lf 0..3 -> global ks16 = (s0>>4) + lf. Use lf = ks16 & 3, skip others.
        if ((ks16 >> 2) == 0) {
            int gks = (s0 >> 4) + ks16;      // global frag 0..7
            int sl = sx;                      // local s 0..63 (sx < 64 when ks16 < 4)
            i32x4 va = *(const i32x4*)((const char*)ab_s[0] + (xr * 72 + sl) * 2);
            i32x4 vb = *(const i32x4*)((const char*)ab_s[1] + (xr * 72 + sl) * 2);
            size_t off = (((size_t)r * 8 + gks) * 64 + ln) * 16;
            *(i32x4*)((char*)aTf + off) = va;
            *(i32x4*)((char*)bTf + off) = vb;
        } else {
            int gks = (s0 >> 4) + (ks16 & 3);
            int sl = (ks16 & 3) * 16 + (ln >> 5) * 8 + 8;   // second 8-s half? no-op guard
            (void)gks; (void)sl;
        }
    }
    // NOTE: the structured write above covers lf 0..1 per piece (f loop) but pieces 2,3
    // handled nothing when ks16>=4. Re-do simply: 256 threads, 4 local frags x 64 lanes = 256.
    {
        int lf = tid >> 6;                   // 0..3 local s-frag (16 s each)
        int ln = tid & 63;
        int xr = ln & 31;
        int sl = lf * 16 + (ln >> 5) * 8;    // local s offset 0..63
        int gks = (s0 >> 4) + lf;            // global frag 0..7
        i32x4 va = *(const i32x4*)((const char*)ab_s[0] + (xr * 72 + sl) * 2);
        i32x4 vb = *(const i32x4*)((const char*)ab_s[1] + (xr * 72 + sl) * 2);
        size_t off = (((size_t)r * 8 + gks) * 64 + ln) * 16;
        *(i32x4*)((char*)aTf + off) = va;
        *(i32x4*)((char*)bTf + off) = vb;
    }
}

// ---------------- kernel 2: fused outer-product + w_out contraction (32x32x16 MFMA) --------
// grid (96 bj, 48 bi), 512 thr (8 waves), O-tile 256m x 128n, LDS 64 KB, 2 blk/CU.
// ph2: wave w owns m-frag w (32 m); bf from LDS lane-linear; af rolling from L2 dup-free.
// ph3: A2 [32p][1024k] bf16, key(p,x) XOR. ph4: (kh 2 x zq 4), wbT rolling 1x, 32 MFMA/wave.
// Pp [2kh][128z][32p] f32 overlays A2-low. 5 lgkm barriers, 1 vmcnt drain.
__global__ __launch_bounds__(512, 4) void k_opm(
    const short* __restrict__ aTf, const short* __restrict__ bTf,
    const short* __restrict__ wbTf, const float* __restrict__ b_out,
    float* __restrict__ out) {
    __shared__ __align__(16) char smem[65536];
    int tid = threadIdx.x, lane = tid & 63, w = tid >> 6;
    int l32 = lane & 31, h = lane >> 5;
    int bj = blockIdx.x, bi = blockIdx.y;

    // ---- stage B (32 KB = 4 res x 8 frags x 1 KB, verbatim) into smem[0,32K)
    const char* gB = (const char*)bTf + (size_t)bj * 32768;
#pragma unroll
    for (int it = 0; it < 4; ++it) {
        int q = it * 8192 + tid * 16;
        __builtin_amdgcn_global_load_lds(
            (const __attribute__((address_space(1))) void*)(gB + q),
            (__attribute__((address_space(3))) void*)(smem + q), 16, 0, 0);
    }
    const char* gA = (const char*)aTf + (size_t)bi * 65536;
    bf16x8 afc = *(const bf16x8*)(gA + (w * 8 + 0) * 1024 + lane * 16);
    asm volatile("s_waitcnt vmcnt(0)" ::: "memory");
    __syncthreads();

    // ---- ph2: O[256x128]; mfma(bf, af): lane l, reg r -> m = w*32 + (l&31),
    //      n = ni*32 + (r&3) + 8*(r>>2) + 4*h
    f32x16 acc[4] = {};
#pragma unroll
    for (int ks = 0; ks < 8; ++ks) {
        bf16x8 bf[4];
#pragma unroll
        for (int ni = 0; ni < 4; ++ni)
            bf[ni] = *(const bf16x8*)(smem + ((ni * 8 + ks) * 1024 + lane * 16));
        bf16x8 afn = afc;
        if (ks < 7) afn = *(const bf16x8*)(gA + (w * 8 + ks + 1) * 1024 + lane * 16);
        __builtin_amdgcn_s_setprio(1);
#pragma unroll
        for (int ni = 0; ni < 4; ++ni)
            acc[ni] = __builtin_amdgcn_mfma_f32_32x32x16_bf16(bf[ni], afc, acc[ni], 0, 0, 0);
        __builtin_amdgcn_s_setprio(0);
        afc = afn;
    }
    lgkm_barrier();   // B reads done -> smem becomes A2 [0,64K)

    // ---- ph3: O -> A2 bf16 [p = (m>>5)*4 + (n>>5)][k = (m&31)*32 + (n&31)]
    //      key(p,x) = ((p&7) ^ (x&7) ^ ((x>>3)&3)) << 4, x = m&31 (lane-varying)
#pragma unroll
    for (int ni = 0; ni < 4; ++ni) {
        int p = w * 4 + ni;
        int x = l32;
        int key = ((p & 7) ^ (x & 7) ^ ((x >> 3) & 3)) << 4;
#pragma unroll
        for (int q = 0; q < 4; ++q) {
            int y0 = 4 * h + 8 * q;
            int byte = (p * 2048 + x * 64 + y0 * 2) ^ key;
            short4 pk;
            pk.x = tobf16(acc[ni][q * 4 + 0]);
            pk.y = tobf16(acc[ni][q * 4 + 1]);
            pk.z = tobf16(acc[ni][q * 4 + 2]);
            pk.w = tobf16(acc[ni][q * 4 + 3]);
            *(short4*)(smem + byte) = pk;
        }
    }

    // pre-issue wb group 0 (global; survives lgkm barrier)
    int kh = w & 1, zq = w >> 1;
    const short* wbase = wbTf + (size_t)((zq * 64 + kh * 32) * 64) * 8;
    bf16x8 wcur[4], wnxt[4];
#pragma unroll
    for (int u = 0; u < 4; ++u)
        wcur[u] = *(const bf16x8*)(wbase + ((u) * 64 + lane) * 8);
    lgkm_barrier();   // A2 visible

    // ---- ph4: wave (kh, zq): out[32p][32z] over k-half; 32 MFMA 32x32x16, dual chain
    f32x16 c2a = {}, c2b = {};
#pragma unroll
    for (int kq = 0; kq < 8; ++kq) {
        if (kq < 7) {
#pragma unroll
            for (int u = 0; u < 4; ++u)
                wnxt[u] = *(const bf16x8*)(wbase + ((kq * 4 + 4 + u) * 64 + lane) * 8);
        }
        bf16x8 a2f[4];
#pragma unroll
        for (int u = 0; u < 4; ++u) {
            int ks16 = kq * 4 + u;                    // local k16 0..31
            int x = kh * 16 + (ks16 >> 1);
            int y0 = (ks16 & 1) * 16 + h * 8;
            int key = ((l32 & 7) ^ (x & 7) ^ ((x >> 3) & 3)) << 4;
            int byte = (l32 * 2048 + x * 64 + y0 * 2) ^ key;
            a2f[u] = *(const bf16x8*)(smem + byte);
        }
        __builtin_amdgcn_s_setprio(1);
        c2a = __builtin_amdgcn_mfma_f32_32x32x16_bf16(a2f[0], wcur[0], c2a, 0, 0, 0);
        c2b = __builtin_amdgcn_mfma_f32_32x32x16_bf16(a2f[1], wcur[1], c2b, 0, 0, 0);
        c2a = __builtin_amdgcn_mfma_f32_32x32x16_bf16(a2f[2], wcur[2], c2a, 0, 0, 0);
        c2b = __builtin_amdgcn_mfma_f32_32x32x16_bf16(a2f[3], wcur[3], c2b, 0, 0, 0);
        __builtin_amdgcn_s_setprio(0);
        if (kq < 7) {
#pragma unroll
            for (int u = 0; u < 4; ++u) wcur[u] = wnxt[u];
        }
    }
    f32x16 c2 = c2a + c2b;
    lgkm_barrier();   // A2 reads done -> [0,32K) becomes Pp

    // ---- Pp write: [kh][z 128][p 32] f32, key = (z&7)<<4. reg r: p = (r&3)+8*(r>>2)+4h
    {
        int z = zq * 32 + l32;
        int zkey = (z & 7) << 4;
#pragma unroll
        for (int q = 0; q < 4; ++q) {
            int p0 = 4 * h + 8 * q;
            int byte = (kh * 16384 + z * 128 + p0 * 4) ^ zkey;
            f32x4 v;
            v[0] = c2[q * 4 + 0]; v[1] = c2[q * 4 + 1];
            v[2] = c2[q * 4 + 2]; v[3] = c2[q * 4 + 3];
            *(f32x4*)(smem + byte) = v;
        }
    }
    lgkm_barrier();

    // ---- reduce kh-halves + store: thread (p = tid&31, z0 = (tid>>5)*8)
    {
        int p = tid & 31;
        int z0 = (tid >> 5) * 8;
        float s[8];
#pragma unroll
        for (int i = 0; i < 8; ++i) {
            int z = z0 + i;
            int a0 = (z * 128 + p * 4) ^ ((z & 7) << 4);
            float u0 = *(const float*)(smem + a0);
            float u1 = *(const float*)(smem + (a0 + 16384));
            s[i] = u0 + u1;
        }
        float4 bo0 = *(const float4*)(b_out + z0);
        float4 bo1 = *(const float4*)(b_out + z0 + 4);
        f32x4 r0, r1;
        r0[0] = (s[0] + bo0.x) * (1.0f / 128.0f);
        r0[1] = (s[1] + bo0.y) * (1.0f / 128.0f);
        r0[2] = (s[2] + bo0.z) * (1.0f / 128.0f);
        r0[3] = (s[3] + bo0.w) * (1.0f / 128.0f);
        r1[0] = (s[4] + bo1.x) * (1.0f / 128.0f);
        r1[1] = (s[5] + bo1.y) * (1.0f / 128.0f);
        r1[2] = (s[6] + bo1.z) * (1.0f / 128.0f);
        r1[3] = (s[7] + bo1.w) * (1.0f / 128.0f);
        int ig = bi * 8 + (p >> 2);
        int jg = bj * 4 + (p & 3);
        float* po = out + ((size_t)ig * R_RES + jg) * CZ + z0;
        *(f32x4*)(po) = r0;
        *(f32x4*)(po + 4) = r1;
    }
}

extern "C" void kernel_launch(void* const* d_in, const int* in_sizes, int n_in,
                              void* d_out, int out_size, void* d_ws, size_t ws_size,
                              hipStream_t stream) {
    const float* M     = (const float*)d_in[0];
    const float* ln_g  = (const float*)d_in[1];
    const float* ln_b  = (const float*)d_in[2];
    const float* w1    = (const float*)d_in[3];
    const float* b1    = (const float*)d_in[4];
    const float* w2    = (const float*)d_in[5];
    const float* b2    = (const float*)d_in[6];
    const float* w_out = (const float*)d_in[7];
    const float* b_out = (const float*)d_in[8];
    float* out = (float*)d_out;

    short* aTf  = (short*)d_ws;             // 384 res x 8 frags x 64 x 8 bf16
    short* bTf  = aTf + 12288 * 128;
    short* wbTf = bTf + 12288 * 128;        // 4 fz x 64 k16 x 64 x 8 bf16
    short* wcT  = wbTf + 128 * 1024;        // 64 x 256 bf16

    k_transpose_wout<<<dim3(16, 2), 256, 0, stream>>>(w_out, wbTf);
    k_pack_w12<<<64, 256, 0, stream>>>(w1, w2, wcT);
    k_ln_proj<<<768, 256, 0, stream>>>(M, ln_g, ln_b, b1, b2, wcT, aTf, bTf);
    k_opm<<<dim3(96, 48), 512, 0, stream>>>(aTf, bTf, wbTf, b_out, out);
}

// Round 13
// 116.466 us; speedup vs baseline: 1.1495x; 1.1495x over previous
//
#include <hip/hip_runtime.h>
#include <hip/hip_bf16.h>

#define R_RES 384
#define S_SEQ 128
#define CM 256
#define CC 32
#define CZ 128

typedef __attribute__((ext_vector_type(8))) short bf16x8;
typedef __attribute__((ext_vector_type(4))) float f32x4;
typedef __attribute__((ext_vector_type(4))) int i32x4;

__device__ __forceinline__ short tobf16(float f) {
    union { __hip_bfloat16 h; short s; } u;
    u.h = __float2bfloat16(f);
    return u.s;
}

__device__ __forceinline__ void lgkm_barrier() {
    asm volatile("s_waitcnt lgkmcnt(0)" ::: "memory");
    __builtin_amdgcn_s_barrier();
    __builtin_amdgcn_sched_barrier(0);
}

// ---------------- kernel 0a: w_out (1024,128) f32 -> wbTf 16x16x32-B-frag tiled bf16 ------
// frag(z16, k32) lane l: z = z16*16 + (l&15), k = k32*32 + (l>>4)*8 + j
__global__ void k_transpose_wout(const float* __restrict__ w_out, short* __restrict__ wbTf) {
    __shared__ float t[64][65];
    int k0 = blockIdx.x * 64;
    int z0 = blockIdx.y * 64;
    int tid = threadIdx.x;
    int c = tid & 63, rg = tid >> 6;
#pragma unroll
    for (int rr = 0; rr < 16; ++rr) {
        int kk = rg * 16 + rr;
        t[kk][c] = w_out[(size_t)(k0 + kk) * CZ + z0 + c];
    }
    __syncthreads();
#pragma unroll
    for (int l = 0; l < 2; ++l) {
        int id = l * 256 + tid;
        int f = id >> 6;
        int z16l = f >> 1, k32l = f & 1;
        int ln = id & 63;
        int zl = z16l * 16 + (ln & 15);
        int kl = k32l * 32 + (ln >> 4) * 8;
        bf16x8 pk;
#pragma unroll
        for (int j = 0; j < 8; ++j) pk[j] = tobf16(t[kl + j][zl]);
        int z16 = blockIdx.y * 4 + z16l;
        int k32 = blockIdx.x * 2 + k32l;
        *(bf16x8*)(wbTf + ((size_t)(z16 * 32 + k32) * 64 + ln) * 8) = pk;
    }
}

// ---------------- kernel 0b: pack w1|w2 (256,32) -> wcT (64,256) bf16 ----------------
__global__ void k_pack_w12(const float* __restrict__ w1, const float* __restrict__ w2,
                           short* __restrict__ wcT) {
    int idx = blockIdx.x * 256 + threadIdx.x;
    int k = idx >> 6, n = idx & 63;
    float v = (n < 32) ? w1[k * CC + n] : w2[k * CC + (n - 32)];
    wcT[n * CM + k] = tobf16(v);
}

// ---------------- kernel 1: LayerNorm + projections -> aTf, bTf fragment-tiled bf16 --------
// aTf frag(fm16, ks32)[lane][8]: m = fm16*16 + (lane&15), s = ks32*32 + (lane>>4)*8 + j
__global__ __launch_bounds__(256) void k_ln_proj(
    const float* __restrict__ M, const float* __restrict__ ln_g, const float* __restrict__ ln_b,
    const float* __restrict__ b1, const float* __restrict__ b2,
    const short* __restrict__ wcT, short* __restrict__ aTf, short* __restrict__ bTf) {
    __shared__ short mnb[64 * 256];
    __shared__ short ab_s[2][32 * 72];
    int r = blockIdx.x >> 1;
    int s0 = (blockIdx.x & 1) * 64;
    int tid = threadIdx.x, lane = tid & 63, w = tid >> 6;
    int g = lane >> 4, r16 = lane & 15;
    float4 gv = *(const float4*)(ln_g + lane * 4);
    float4 bv = *(const float4*)(ln_b + lane * 4);
    for (int it = 0; it < 16; ++it) {
        int sl = it * 4 + w;
        float4 v = *(const float4*)(M + ((size_t)(s0 + sl) * R_RES + r) * CM + lane * 4);
        float sum = v.x + v.y + v.z + v.w;
        float sq = v.x * v.x + v.y * v.y + v.z * v.z + v.w * v.w;
#pragma unroll
        for (int off = 32; off; off >>= 1) {
            sum += __shfl_xor(sum, off);
            sq  += __shfl_xor(sq, off);
        }
        float mu = sum * (1.0f / 256.0f);
        float var = sq * (1.0f / 256.0f) - mu * mu;
        float rstd = rsqrtf(var + 1e-5f);
        short4 mnp;
        mnp.x = tobf16((v.x - mu) * rstd * gv.x + bv.x);
        mnp.y = tobf16((v.y - mu) * rstd * gv.y + bv.y);
        mnp.z = tobf16((v.z - mu) * rstd * gv.z + bv.z);
        mnp.w = tobf16((v.w - mu) * rstd * gv.w + bv.w);
        int byte = sl * 512 + lane * 8;
        byte ^= ((sl & 7) << 4);
        *(short4*)((char*)mnb + byte) = mnp;
    }
    __syncthreads();
    f32x4 acc[4] = {{0,0,0,0},{0,0,0,0},{0,0,0,0},{0,0,0,0}};
    int srow = w * 16 + r16;
#pragma unroll
    for (int ks = 0; ks < 8; ++ks) {
        int byte = srow * 512 + ks * 64 + g * 16;
        byte ^= ((srow & 7) << 4);
        bf16x8 af = *(const bf16x8*)((const char*)mnb + byte);
#pragma unroll
        for (int nt = 0; nt < 4; ++nt) {
            bf16x8 bf = *(const bf16x8*)(wcT + (nt * 16 + r16) * CM + ks * 32 + g * 8);
            acc[nt] = __builtin_amdgcn_mfma_f32_16x16x32_bf16(af, bf, acc[nt], 0, 0, 0);
        }
    }
#pragma unroll
    for (int nt = 0; nt < 4; ++nt) {
        int n = nt * 16 + r16;
        int x = n & 31, sel = n >> 5;
        float bias = sel ? b2[x] : b1[x];
#pragma unroll
        for (int rr = 0; rr < 4; ++rr) {
            int sl = w * 16 + g * 4 + rr;
            ab_s[sel][x * 72 + sl] = tobf16(acc[nt][rr] + bias);
        }
    }
    __syncthreads();
    int piece = tid >> 6;
    int fl = piece >> 1, kl = piece & 1;
    int ln = tid & 63;
    int x = fl * 16 + (ln & 15);
    int s_loc = kl * 32 + (ln >> 4) * 8;
    i32x4 va = *(const i32x4*)((const char*)ab_s[0] + (x * 72 + s_loc) * 2);
    i32x4 vb = *(const i32x4*)((const char*)ab_s[1] + (x * 72 + s_loc) * 2);
    size_t off = ((((size_t)r * 2 + fl) * 4 + (s0 >> 5) + kl) * 64 + ln) * 16;
    *(i32x4*)((char*)aTf + off) = va;
    *(i32x4*)((char*)bTf + off) = vb;
}

// ---------------- kernel 2: persistent cross-tile-pipelined fused kernel ----------------
// 256 blocks x 512 thr (8 waves), 36 tiles/block of 128x128 O (4res x 4res).
// __launch_bounds__(512,2): wb[2][16] (128 regs) genuinely resident (R10-verified).
// LDS 144K: B dbuf [0,64K), A2 dbuf [64K,128K), Pp [128K,144K). 1 block/CU.
// Steady iter: {ph4(it) || ph2(it+1) || stage B(it+2)} -> Pp -> bar -> {ph3(it+1) || reduce(it)} -> bar
__global__ __launch_bounds__(512, 2) void k_opm(
    const short* __restrict__ aTf, const short* __restrict__ bTf,
    const short* __restrict__ wbTf, const float* __restrict__ b_out,
    float* __restrict__ out) {
    __shared__ __align__(16) char smem[147456];
    int tid = threadIdx.x, lane = tid & 63, w = tid >> 6;
    int g = lane >> 4, r16 = lane & 15;
    int wm = w;                      // ph2: wave owns m-rows [wm*16, wm*16+16)
    int kh = w & 1, zq = w >> 1;     // ph4 role: k-half, z-quarter

    int t0 = blockIdx.x * 36;
    const char* Ab = (const char*)aTf;
    const char* Bb = (const char*)bTf;

    // ---- issue B(t0)->buf0, B(t0+1)->buf1 staging first (async)
    {
        const char* gB0 = Bb + (size_t)(t0 % 96) * 32768;
        const char* gB1 = Bb + (size_t)((t0 + 1) % 96) * 32768;
#pragma unroll
        for (int q = 0; q < 4; ++q) {
            __builtin_amdgcn_global_load_lds(
                (const __attribute__((address_space(1))) void*)(gB0 + q * 8192 + tid * 16),
                (__attribute__((address_space(3))) void*)(smem + q * 8192 + tid * 16), 16, 0, 0);
            __builtin_amdgcn_global_load_lds(
                (const __attribute__((address_space(1))) void*)(gB1 + q * 8192 + tid * 16),
                (__attribute__((address_space(3))) void*)(smem + 32768 + q * 8192 + tid * 16), 16, 0, 0);
        }
    }
    // ---- persistent wbT slice (z in [zq*32,+32), k in [kh*512,+512)); static idx -> resident
    bf16x8 wb[2][16];
#pragma unroll
    for (int zt = 0; zt < 2; ++zt)
#pragma unroll
        for (int ks2 = 0; ks2 < 16; ++ks2)
            wb[zt][ks2] = *(const bf16x8*)(wbTf +
                (((size_t)(zq * 2 + zt) * 32 + kh * 16 + ks2) * 64 + lane) * 8);

    int pR = tid >> 5;               // reduce role: p row (0..15)
    int zR = (tid & 31) * 4;         // reduce role: z quad
    float4 bo4 = *(const float4*)(b_out + zR);

    bf16x8 afc = *(const bf16x8*)(Ab + (size_t)((t0 / 96) * 8 + wm) * 4096 + lane * 16);
    asm volatile("s_waitcnt vmcnt(0)" ::: "memory");
    __syncthreads();

    // ---- prologue: ph2(t0) from buf0 -> acc; ph3(t0) -> A2_0
    f32x4 acc[8] = {};
    {
        const char* gAc = Ab + (size_t)((t0 / 96) * 8 + wm) * 4096;
        const char* gAn = Ab + (size_t)(((t0 + 1) / 96) * 8 + wm) * 4096;
#pragma unroll
        for (int ks = 0; ks < 4; ++ks) {
            bf16x8 bf[8];
#pragma unroll
            for (int ni = 0; ni < 8; ++ni)
                bf[ni] = *(const bf16x8*)(smem + ((ni * 4 + ks) * 64 + lane) * 16);
            bf16x8 afn = (ks < 3) ? *(const bf16x8*)(gAc + (ks + 1) * 1024 + lane * 16)
                                  : *(const bf16x8*)(gAn + lane * 16);
            __builtin_amdgcn_s_setprio(1);
#pragma unroll
            for (int ni = 0; ni < 8; ++ni)
                acc[ni] = __builtin_amdgcn_mfma_f32_16x16x32_bf16(bf[ni], afc, acc[ni], 0, 0, 0);
            __builtin_amdgcn_s_setprio(0);
            afc = afn;
        }
    }
    lgkm_barrier();   // buf0 reads done
#pragma unroll
    for (int ni = 0; ni < 8; ++ni) {
        int x = (wm & 1) * 16 + r16;
        int p = (wm >> 1) * 4 + (ni >> 1);
        int y0 = (ni & 1) * 16 + g * 4;
        int byte = (p * 2048 + x * 64 + y0 * 2) ^ (((p & 7) ^ (x & 7)) << 4);
        short4 pk;
        pk.x = tobf16(acc[ni][0]);
        pk.y = tobf16(acc[ni][1]);
        pk.z = tobf16(acc[ni][2]);
        pk.w = tobf16(acc[ni][3]);
        *(short4*)(smem + 65536 + byte) = pk;
    }
    lgkm_barrier();   // A2_0 visible

    for (int it = 0; it < 36; ++it) {
        int t = t0 + it;
        bool hasN = (it < 35);
        int tc = t + 1;                                  // ph2 tile
        int tnn = (it < 34) ? t + 2 : t0 + 35;           // next af tile (clamped)

        // ---- stage B(it+2) into buf (it&1) (its ph2(it) reads finished last iteration)
        if (it < 34) {
            const char* gB = Bb + (size_t)((t + 2) % 96) * 32768;
            char* dst = smem + (it & 1) * 32768;
#pragma unroll
            for (int q = 0; q < 4; ++q)
                __builtin_amdgcn_global_load_lds(
                    (const __attribute__((address_space(1))) void*)(gB + q * 8192 + tid * 16),
                    (__attribute__((address_space(3))) void*)(dst + q * 8192 + tid * 16), 16, 0, 0);
        }

        const char* A2r = smem + 65536 + (it & 1) * 32768;
        const char* Bn  = smem + ((it + 1) & 1) * 32768;
        const char* gAc = Ab + (size_t)((tc / 96) * 8 + wm) * 4096;
        const char* gAn = Ab + (size_t)((tnn / 96) * 8 + wm) * 4096;

        // ---- merged compute: ph4(it) + ph2(it+1), co-scheduled
        f32x4 c0 = {0,0,0,0}, c1 = {0,0,0,0};
        f32x4 acc2[8] = {};
#pragma unroll
        for (int ks = 0; ks < 4; ++ks) {
            // half 1: ks2 = ks*4 + {0,1}, ph2 ni 0..3
            bf16x8 a2f0, a2f1, bfh[4];
            {
                int x = kh * 16 + ks * 4 + 0;
                a2f0 = *(const bf16x8*)(A2r + ((r16 * 2048 + x * 64 + g * 16)
                        ^ ((((r16 & 7) ^ (x & 7))) << 4)));
                x = kh * 16 + ks * 4 + 1;
                a2f1 = *(const bf16x8*)(A2r + ((r16 * 2048 + x * 64 + g * 16)
                        ^ ((((r16 & 7) ^ (x & 7))) << 4)));
            }
            if (hasN) {
#pragma unroll
                for (int ni = 0; ni < 4; ++ni)
                    bfh[ni] = *(const bf16x8*)(Bn + ((ni * 4 + ks) * 64 + lane) * 16);
            }
            __builtin_amdgcn_s_setprio(1);
            c0 = __builtin_amdgcn_mfma_f32_16x16x32_bf16(wb[0][ks * 4 + 0], a2f0, c0, 0, 0, 0);
            c1 = __builtin_amdgcn_mfma_f32_16x16x32_bf16(wb[1][ks * 4 + 0], a2f0, c1, 0, 0, 0);
            c0 = __builtin_amdgcn_mfma_f32_16x16x32_bf16(wb[0][ks * 4 + 1], a2f1, c0, 0, 0, 0);
            c1 = __builtin_amdgcn_mfma_f32_16x16x32_bf16(wb[1][ks * 4 + 1], a2f1, c1, 0, 0, 0);
            if (hasN) {
#pragma unroll
                for (int ni = 0; ni < 4; ++ni)
                    acc2[ni] = __builtin_amdgcn_mfma_f32_16x16x32_bf16(bfh[ni], afc, acc2[ni], 0, 0, 0);
            }
            __builtin_amdgcn_s_setprio(0);
            // half 2: ks2 = ks*4 + {2,3}, ph2 ni 4..7, af roll
            bf16x8 a2f2, a2f3;
            {
                int x = kh * 16 + ks * 4 + 2;
                a2f2 = *(const bf16x8*)(A2r + ((r16 * 2048 + x * 64 + g * 16)
                        ^ ((((r16 & 7) ^ (x & 7))) << 4)));
                x = kh * 16 + ks * 4 + 3;
                a2f3 = *(const bf16x8*)(A2r + ((r16 * 2048 + x * 64 + g * 16)
                        ^ ((((r16 & 7) ^ (x & 7))) << 4)));
            }
            if (hasN) {
#pragma unroll
                for (int ni = 0; ni < 4; ++ni)
                    bfh[ni] = *(const bf16x8*)(Bn + (((ni + 4) * 4 + ks) * 64 + lane) * 16);
            }
            bf16x8 afn = afc;
            if (hasN) afn = (ks < 3) ? *(const bf16x8*)(gAc + (ks + 1) * 1024 + lane * 16)
                                     : *(const bf16x8*)(gAn + lane * 16);
            __builtin_amdgcn_s_setprio(1);
            c0 = __builtin_amdgcn_mfma_f32_16x16x32_bf16(wb[0][ks * 4 + 2], a2f2, c0, 0, 0, 0);
            c1 = __builtin_amdgcn_mfma_f32_16x16x32_bf16(wb[1][ks * 4 + 2], a2f2, c1, 0, 0, 0);
            c0 = __builtin_amdgcn_mfma_f32_16x16x32_bf16(wb[0][ks * 4 + 3], a2f3, c0, 0, 0, 0);
            c1 = __builtin_amdgcn_mfma_f32_16x16x32_bf16(wb[1][ks * 4 + 3], a2f3, c1, 0, 0, 0);
            if (hasN) {
#pragma unroll
                for (int ni = 0; ni < 4; ++ni)
                    acc2[ni + 4] = __builtin_amdgcn_mfma_f32_16x16x32_bf16(bfh[ni], afc, acc2[ni + 4], 0, 0, 0);
            }
            __builtin_amdgcn_s_setprio(0);
            afc = afn;
        }

        // ---- Pp write: [kh][p=r16][z] f32 at [128K,144K), ^((r16&7)<<4)
        {
            int b0 = (kh * 8192 + r16 * 512 + (zq * 32 + g * 4) * 4) ^ ((r16 & 7) << 4);
            int b1 = (kh * 8192 + r16 * 512 + (zq * 32 + 16 + g * 4) * 4) ^ ((r16 & 7) << 4);
            *(f32x4*)(smem + 131072 + b0) = c0;
            *(f32x4*)(smem + 131072 + b1) = c1;
        }
        lgkm_barrier();   // Pp visible; all A2r/Bn reads done

        // ---- ph3(it+1): acc2 -> A2 buf ((it+1)&1)
        if (hasN) {
            char* A2w = smem + 65536 + ((it + 1) & 1) * 32768;
#pragma unroll
            for (int ni = 0; ni < 8; ++ni) {
                int x = (wm & 1) * 16 + r16;
                int p = (wm >> 1) * 4 + (ni >> 1);
                int y0 = (ni & 1) * 16 + g * 4;
                int byte = (p * 2048 + x * 64 + y0 * 2) ^ (((p & 7) ^ (x & 7)) << 4);
                short4 pk;
                pk.x = tobf16(acc2[ni][0]);
                pk.y = tobf16(acc2[ni][1]);
                pk.z = tobf16(acc2[ni][2]);
                pk.w = tobf16(acc2[ni][3]);
                *(short4*)(A2w + byte) = pk;
            }
        }

        // ---- reduce kh-halves + coalesced store for tile it
        {
            int base = (pR * 512 + zR * 4) ^ ((pR & 7) << 4);
            f32x4 v0 = *(const f32x4*)(smem + 131072 + base);
            f32x4 v1 = *(const f32x4*)(smem + 131072 + 8192 + base);
            f32x4 res;
            res[0] = (v0[0] + v1[0] + bo4.x) * (1.0f / 128.0f);
            res[1] = (v0[1] + v1[1] + bo4.y) * (1.0f / 128.0f);
            res[2] = (v0[2] + v1[2] + bo4.z) * (1.0f / 128.0f);
            res[3] = (v0[3] + v1[3] + bo4.w) * (1.0f / 128.0f);
            int bi4 = t / 96, bj4 = t % 96;
            int ig = bi4 * 4 + (pR >> 2);
            int jg = bj4 * 4 + (pR & 3);
            *(f32x4*)(out + ((size_t)ig * R_RES + jg) * CZ + zR) = res;
        }

        // ---- end barrier: A2(it+1) visible, Pp reads done, B staging drained
        asm volatile("s_waitcnt vmcnt(0)" ::: "memory");
        __syncthreads();
    }
}

extern "C" void kernel_launch(void* const* d_in, const int* in_sizes, int n_in,
                              void* d_out, int out_size, void* d_ws, size_t ws_size,
                              hipStream_t stream) {
    const float* M     = (const float*)d_in[0];
    const float* ln_g  = (const float*)d_in[1];
    const float* ln_b  = (const float*)d_in[2];
    const float* w1    = (const float*)d_in[3];
    const float* b1    = (const float*)d_in[4];
    const float* w2    = (const float*)d_in[5];
    const float* b2    = (const float*)d_in[6];
    const float* w_out = (const float*)d_in[7];
    const float* b_out = (const float*)d_in[8];
    float* out = (float*)d_out;

    short* aTf  = (short*)d_ws;             // 12288 x 128 bf16, fragment-tiled
    short* bTf  = aTf + 12288 * 128;        // 12288 x 128 bf16, fragment-tiled
    short* wbTf = bTf + 12288 * 128;        // 128 x 1024 bf16, 16x16-B-frag tiled
    short* wcT  = wbTf + 128 * 1024;        // 64 x 256 bf16

    k_transpose_wout<<<dim3(16, 2), 256, 0, stream>>>(w_out, wbTf);
    k_pack_w12<<<64, 256, 0, stream>>>(w1, w2, wcT);
    k_ln_proj<<<768, 256, 0, stream>>>(M, ln_g, ln_b, b1, b2, wcT, aTf, bTf);
    k_opm<<<256, 512, 0, stream>>>(aTf, bTf, wbTf, b_out, out);
}